// Round 8
// baseline (385.272 us; speedup 1.0000x reference)
//
#include <hip/hip_runtime.h>
#include <stdint.h>

typedef __attribute__((ext_vector_type(8))) short short8;
typedef __attribute__((ext_vector_type(4))) float f32x4;

#define DEVFN static __device__ __forceinline__

// ---------------- helpers ----------------
DEVFN float bf2f(uint16_t u) { union { uint32_t i; float f; } v; v.i = ((uint32_t)u) << 16; return v.f; }
DEVFN uint16_t f2bf(float f) {
  union { float f; uint32_t i; } v; v.f = f;
  uint32_t u = v.i;
  u += 0x7fffu + ((u >> 16) & 1u);   // RNE
  return (uint16_t)(u >> 16);
}
DEVFN int imin(int a, int b) { return a < b ? a : b; }

DEVFN void gl_lds16(const void* g, void* l) {
  __builtin_amdgcn_global_load_lds(
      (__attribute__((address_space(1))) void*)(void*)g,
      (__attribute__((address_space(3))) void*)l, 16, 0, 0);
}

DEVFN f32x4 mfma16(short8 a, short8 b, f32x4 c) {
  return __builtin_amdgcn_mfma_f32_16x16x32_bf16(a, b, c, 0, 0, 0);
}

// ---------------- workspace layout (bytes) ----------------
static constexpr size_t OFF_XP   = 0;          // bf16 [64][232][232][4]  x: masked, padded(+3), NHWC4
static constexpr size_t OFF_W1T  = 27557888;   // bf16 [7][64][32]        w1t[kh][oc][kw*4+ic]
static constexpr size_t OFF_W2T  = 27586560;   // bf16 [49][768][64]      w2t[kh*7+kw][oc][ic]
static constexpr size_t OFF_Y1   = 32403456;   // bf16 [64][112][112][64] conv1 out (active cells only)
static constexpr size_t OFF_P1   = 135163904;  // bf16 [64][62][62][64]   pool1 out, padded(+3), NHWC
static constexpr size_t OFF_Y2   = 166653952;  // bf16 [64][28][28][768]  conv2 out (active cells only)
static constexpr size_t OFF_LIST = 243724288;  // int [12544] active cell list, SORTED
static constexpr size_t OFF_CNT  = 243774464;  // int cnts[49] + int total
static constexpr size_t WS_NEED  = 243774664;

// ---------------- stage 0a: per-block mask counts ----------------
__global__ __launch_bounds__(256) void k_count(const int* __restrict__ masks, int* __restrict__ cnts) {
  int b = blockIdx.x;
  int gid = b * 256 + threadIdx.x;   // 49*256 = 12544 exactly
  unsigned long long m = __ballot(masks[gid] != 0);
  __shared__ int wsum[4];
  if ((threadIdx.x & 63) == 0) wsum[threadIdx.x >> 6] = __popcll(m);
  __syncthreads();
  if (threadIdx.x == 0) cnts[b] = wsum[0] + wsum[1] + wsum[2] + wsum[3];
}

// ---------------- stage 0b: deterministic sorted compaction ----------------
__global__ __launch_bounds__(256) void k_emit(const int* __restrict__ masks, const int* __restrict__ cnts,
                                              int* __restrict__ list, int* __restrict__ total) {
  int b = blockIdx.x;
  int gid = b * 256 + threadIdx.x;
  int lane = threadIdx.x & 63, wave = threadIdx.x >> 6;
  int base = 0;
  for (int i = 0; i < b; ++i) base += cnts[i];
  bool f = masks[gid] != 0;
  unsigned long long m = __ballot(f);
  __shared__ int wcnt[4];
  if (lane == 0) wcnt[wave] = __popcll(m);
  __syncthreads();
  int woff = 0;
  for (int i = 0; i < wave; ++i) woff += wcnt[i];
  if (f) list[base + woff + __popcll(m & ((1ull << lane) - 1ull))] = gid;
  if (b == 48 && threadIdx.x == 0)
    *total = base + wcnt[0] + wcnt[1] + wcnt[2] + wcnt[3];
}

// ---------------- stage 1: x -> masked bf16 NHWC4 padded ----------------
__global__ __launch_bounds__(256) void k_prep(const float* __restrict__ x, const int* __restrict__ masks,
                                              uint16_t* __restrict__ xp) {
  int gid = blockIdx.x * 256 + threadIdx.x;   // 64*232*232 = 3,444,736 exactly
  int b = gid / 53824;
  int rc = gid - b * 53824;
  int r2 = rc / 232;
  int c2 = rc - r2 * 232;
  int r = r2 - 3, c = c2 - 3;
  uint16_t o0 = 0, o1 = 0, o2 = 0;
  if ((unsigned)r < 224u && (unsigned)c < 224u) {
    if (masks[b * 196 + (r >> 4) * 14 + (c >> 4)]) {
      const float* px = x + (((size_t)b * 3) * 224 + r) * 224 + c;
      o0 = f2bf(px[0]);
      o1 = f2bf(px[50176]);
      o2 = f2bf(px[100352]);
    }
  }
  ushort4 o; o.x = o0; o.y = o1; o.z = o2; o.w = 0;
  *(ushort4*)(xp + (size_t)gid * 4) = o;
}

// ---------------- stage 2: weight transforms ----------------
__global__ __launch_bounds__(256) void k_wt(const float* __restrict__ w1, const float* __restrict__ w2,
                                            uint16_t* __restrict__ w1t, uint16_t* __restrict__ w2t) {
  int gid = blockIdx.x * 256 + threadIdx.x;   // 14336 + 2408448 = 2,422,784 exactly
  if (gid < 14336) {
    int kh = gid / 2048; int r = gid - kh * 2048;
    int oc = r >> 5, slot = r & 31;
    int kw = slot >> 2, ic = slot & 3;
    float v = 0.f;
    if (kw < 7 && ic < 3) v = w1[((oc * 3 + ic) * 7 + kh) * 7 + kw];
    w1t[gid] = f2bf(v);
  } else {
    int g2 = gid - 14336;
    int khw = g2 / 49152; int r = g2 - khw * 49152;
    int oc = r >> 6, ic = r & 63;
    int kh = khw / 7, kw = khw - kh * 7;
    w2t[g2] = f2bf(w2[((oc * 64 + ic) * 7 + kh) * 7 + kw]);
  }
}

// ---------------- stage 3: conv1 (7x7 s2) — barrier-free K-loop ----------------
__global__ __launch_bounds__(256, 3) void k_conv1(const uint16_t* __restrict__ xp, const uint16_t* __restrict__ w1t,
                                                  const int* __restrict__ list, const int* __restrict__ count,
                                                  uint16_t* __restrict__ y1) {
  __shared__ uint16_t sB[7 * 64 * 32];   // 28 KB: whole w1t resident
  __shared__ int sc[2];

  int cnt = *count;
  int blk = blockIdx.x;
  if (blk * 2 >= cnt) return;
  int tid = threadIdx.x, lane = tid & 63, wave = tid >> 6;
  int csw = (lane & 3) ^ ((lane >> 2) & 3);

  {
    const char* wg = (const char*)w1t;
    char* wl = (char*)sB;
#pragma unroll
    for (int t = 0; t < 7; ++t) {
      int ldsoff = t * 4096 + wave * 1024;
      int goff = t * 4096 + (wave * 16 + (lane >> 2)) * 64 + csw * 16;
      gl_lds16(wg + goff, wl + ldsoff);
    }
  }
  if (tid < 2) sc[tid] = list[imin(blk * 2 + tid, cnt - 1)];
  __syncthreads();

  int wm = wave * 32, mrow = lane & 15, kg = lane >> 4;

  const uint16_t* baseA[2];
#pragma unroll
  for (int i = 0; i < 2; ++i) {
    int row = wm + 16 * i + mrow;
    int cell = sc[row >> 6];
    int b = cell / 196, cc = cell - b * 196;
    int ci = cc / 14, cj = cc - ci * 14;
    int p = row & 63;
    int oh = ci * 8 + (p >> 3), ow = cj * 8 + (p & 7);
    baseA[i] = xp + (((size_t)(b * 232 + 2 * oh)) * 232 + 2 * ow) * 4 + kg * 8;
  }
  int ksw = (kg ^ (mrow & 3)) * 8;

  f32x4 acc[2][4];
#pragma unroll
  for (int i = 0; i < 2; ++i)
#pragma unroll
    for (int j = 0; j < 4; ++j) acc[i][j] = f32x4{0.f, 0.f, 0.f, 0.f};

#pragma unroll
  for (int kh = 0; kh < 7; ++kh) {
    short8 a0 = *(const short8*)(baseA[0] + kh * 928);
    short8 a1 = *(const short8*)(baseA[1] + kh * 928);
    const uint16_t* Bk = sB + kh * 2048;
#pragma unroll
    for (int j = 0; j < 4; ++j) {
      short8 bj = *(const short8*)(Bk + (16 * j + mrow) * 32 + ksw);
      acc[0][j] = mfma16(a0, bj, acc[0][j]);
      acc[1][j] = mfma16(a1, bj, acc[1][j]);
    }
  }

#pragma unroll
  for (int i = 0; i < 2; ++i) {
    int rbase = wm + 16 * i;
    int cellidx = blk * 2 + (rbase >> 6);
    if (cellidx >= cnt) continue;
    int cell = sc[rbase >> 6];
    int b = cell / 196, cc = cell - b * 196;
    int ci = cc / 14, cj = cc - ci * 14;
#pragma unroll
    for (int j = 0; j < 4; ++j) {
      int oc = 16 * j + mrow;
#pragma unroll
      for (int r = 0; r < 4; ++r) {
        int row = rbase + kg * 4 + r;
        int p = row & 63;
        int oh = ci * 8 + (p >> 3), ow = cj * 8 + (p & 7);
        float v = acc[i][j][r];
        v = v > 0.f ? v : 0.f;
        y1[(((size_t)(b * 112 + oh)) * 112 + ow) * 64 + oc] = f2bf(v);
      }
    }
  }
}

// ---------------- stage 4: MaxBlurPool1 (112 -> 56), mask-aware, writes padded p1 ----------------
__global__ __launch_bounds__(256) void k_pool1(const uint16_t* __restrict__ y1, const int* __restrict__ masks,
                                               uint16_t* __restrict__ p1) {
  __shared__ uint16_t sY[18 * 18 * 64];  // 41,472 B
  int b = blockIdx.y;
  int tile = blockIdx.x;
  int tr = tile >> 3, tc = tile & 7;
  int pr0 = tr * 8, pc0 = tc * 8;
  int R0 = 2 * pr0 - 7, C0 = 2 * pc0 - 7;
  int tid = threadIdx.x;
  const int* mb = masks + b * 196;

  for (int idx = tid; idx < 2592; idx += 256) {
    int pix = idx >> 3, ch = idx & 7;
    int pr = pix / 18, pc = pix - pr * 18;
    int r = R0 + pr, c = C0 + pc;
    short8 v = {0, 0, 0, 0, 0, 0, 0, 0};
    if ((unsigned)r < 112u && (unsigned)c < 112u && mb[(r >> 3) * 14 + (c >> 3)])
      v = *(const short8*)(y1 + (((size_t)(b * 112 + r)) * 112 + c) * 64 + ch * 8);
    *(short8*)(sY + ((size_t)(pr * 18 + pc)) * 64 + ch * 8) = v;
  }
  __syncthreads();

  for (int it = tid; it < 512; it += 256) {
    int opix = it >> 3, ch = it & 7;
    int lr = opix >> 3, lc = opix & 7;
    int pr = pr0 + lr, pc = pc0 + lc;
    if (pr >= 62 || pc >= 62) continue;
    int oh = pr - 3, ow = pc - 3;
    float acc[8] = {0.f, 0.f, 0.f, 0.f, 0.f, 0.f, 0.f, 0.f};
    if ((unsigned)oh < 56u && (unsigned)ow < 56u) {
      float hm_prev[3][8];
#pragma unroll
      for (int dd = 0; dd < 4; ++dd) {
        float yv[4][8];
        const uint16_t* src = sY + ((size_t)((2 * lr + dd) * 18 + 2 * lc)) * 64 + ch * 8;
#pragma unroll
        for (int e = 0; e < 4; ++e) {
          short8 t8 = *(const short8*)(src + e * 64);
#pragma unroll
          for (int k = 0; k < 8; ++k) yv[e][k] = bf2f((uint16_t)t8[k]);
        }
        float hm[3][8];
#pragma unroll
        for (int e = 0; e < 3; ++e) {
          int qc = 2 * ow - 1 + e;
          float cv = ((unsigned)qc <= 110u) ? 1.f : 0.f;
#pragma unroll
          for (int k = 0; k < 8; ++k) hm[e][k] = cv * fmaxf(yv[e][k], yv[e + 1][k]);
        }
        if (dd > 0) {
          int d = dd - 1;
          int qr = 2 * oh - 1 + d;
          if ((unsigned)qr <= 110u) {
            float wd = (d == 1) ? 2.f : 1.f;
#pragma unroll
            for (int e = 0; e < 3; ++e) {
              float w = wd * ((e == 1) ? 2.f : 1.f);
#pragma unroll
              for (int k = 0; k < 8; ++k) acc[k] += w * fmaxf(hm_prev[e][k], hm[e][k]);
            }
          }
        }
#pragma unroll
        for (int e = 0; e < 3; ++e)
#pragma unroll
          for (int k = 0; k < 8; ++k) hm_prev[e][k] = hm[e][k];
      }
#pragma unroll
      for (int k = 0; k < 8; ++k) acc[k] *= (1.f / 16.f);
    }
    short8 o;
#pragma unroll
    for (int k = 0; k < 8; ++k) o[k] = (short)f2bf(acc[k]);
    *(short8*)(p1 + (((size_t)(b * 62 + pr)) * 62 + pc) * 64 + ch * 8) = o;
  }
}

// ---------------- stage 5: conv2 (7x7 s2) — MFMA 256x128, 4 waves x (64 rows x full N), 2-barrier ----
// R8: model correction — one 16x16x32 MFMA ~ 19.4 SIMD-cyc (m06 ceiling is per-CU), so R6's 1306
// cyc/block-tap = port-bound (96 KB LDS traffic ~ 750-1100 cyc) with MFMA (620) hidden under it;
// MfmaUtil 46% == 620/1306 exactly. Lever = LDS-port bytes per unit work. Each wave now computes
// 64x128 (full N): per block-tap port = A 32K + B 16K staged + 96K read = 144 KB for 2x R6's work
// (-25%/work), per-SIMD MFMA 1240 ~ port 1125-1700 -> balanced pipes. B traffic halves globally.
// Serial-ks (12 live frags) keeps arch VGPR ~90 + 128 acc -> fits (256,2), no spill (R4 canary:
// WRITE_SIZE must stay ~38 GB). 2-barrier loop (R1/R7 twice proved dbuf/pipelining loses residency).
__global__ __launch_bounds__(256, 2) void k_conv2(const uint16_t* __restrict__ p1, const uint16_t* __restrict__ w2t,
                                                  const int* __restrict__ list, const int* __restrict__ count,
                                                  uint16_t* __restrict__ y2) {
  __shared__ uint16_t sA[256 * 64];   // 32 KB  A[row][ic]
  __shared__ uint16_t sBt[128 * 64];  // 16 KB  B^T[oc][ic]
  __shared__ int scs[64];

  int cnt = *count;
  int gx = blockIdx.x;
  int xcd = gx & 7, s = gx >> 3;
  int y = s % 6, mtl = s / 6;
  int mt = xcd + 8 * mtl;            // 0..199 (grid 8*25*6 = 1200 covers worst-case cnt=12544)
  if (mt * 64 >= cnt) return;
  int ocb = y * 128;
  int tid = threadIdx.x, lane = tid & 63, wave = tid >> 6;   // 4 waves
  int csw = (lane & 7) ^ ((lane >> 3) & 7);

  if (tid < 64) scs[tid] = list[imin(mt * 64 + tid, cnt - 1)];
  __syncthreads();

  int mrow = lane & 15, kg = lane >> 4;

  // A staging: rows r = wave*64 + t*8 + (lane>>3), t=0..7 -> 256 rows; chunk csw pre-swizzled.
  const char* gA[8];
#pragma unroll
  for (int t = 0; t < 8; ++t) {
    int r = wave * 64 + t * 8 + (lane >> 3);
    int cell = scs[r >> 2];
    int b = cell / 196, cc = cell - b * 196;
    int ci = cc / 14, cj = cc - ci * 14;
    int p = r & 3;
    int oh = 2 * ci + (p >> 1), ow = 2 * cj + (p & 1);
    gA[t] = (const char*)p1 + (((size_t)(b * 62 + 2 * oh)) * 62 + 2 * ow) * 128 + csw * 16;
  }
  // B staging: oc rows wave*32 + t*8 + (lane>>3), t=0..3 -> 128 oc.
  const char* gB[4];
#pragma unroll
  for (int t = 0; t < 4; ++t) {
    int oc = ocb + wave * 32 + t * 8 + (lane >> 3);
    gB[t] = (const char*)w2t + (size_t)oc * 128 + csw * 16;
  }

  f32x4 acc[4][8];
#pragma unroll
  for (int i = 0; i < 4; ++i)
#pragma unroll
    for (int j = 0; j < 8; ++j) acc[i][j] = f32x4{0.f, 0.f, 0.f, 0.f};

  int sw8 = mrow & 7;
  int k0 = (kg ^ sw8) * 8;          // ks=0 chunk offset (elems)
  int k1 = ((4 + kg) ^ sw8) * 8;    // ks=1 chunk offset
  int aoff = (wave * 64 + mrow) * 64;   // wave's A base row (elems; +1024*i per frag)
  int boff = mrow * 64;                 // B base row (full 128 oc; +1024*j per frag)
  char* la = (char*)sA + wave * 8192;   // 64 rows * 128 B
  char* lb = (char*)sBt + wave * 4096;  // 32 rows * 128 B

  int kh = 0, kw = 0;

#pragma unroll 1
  for (int it = 0; it < 49; ++it) {
    size_t offA = (size_t)(kh * 62 + kw) * 128;
    size_t offB = (size_t)it * 98304;   // 768*64 elems * 2 B per tap
#pragma unroll
    for (int t = 0; t < 8; ++t) gl_lds16(gA[t] + offA, la + t * 1024);
#pragma unroll
    for (int t = 0; t < 4; ++t) gl_lds16(gB[t] + offB, lb + t * 1024);
    __syncthreads();
    {
      short8 a[4], b[8];
#pragma unroll
      for (int i = 0; i < 4; ++i) a[i] = *(const short8*)(sA + aoff + 1024 * i + k0);
#pragma unroll
      for (int j = 0; j < 8; ++j) b[j] = *(const short8*)(sBt + boff + 1024 * j + k0);
      __builtin_amdgcn_sched_barrier(0);
      __builtin_amdgcn_s_setprio(1);
#pragma unroll
      for (int i = 0; i < 4; ++i)
#pragma unroll
        for (int j = 0; j < 8; ++j)
          acc[i][j] = mfma16(a[i], b[j], acc[i][j]);
      __builtin_amdgcn_s_setprio(0);
      __builtin_amdgcn_sched_barrier(0);
#pragma unroll
      for (int i = 0; i < 4; ++i) a[i] = *(const short8*)(sA + aoff + 1024 * i + k1);
#pragma unroll
      for (int j = 0; j < 8; ++j) b[j] = *(const short8*)(sBt + boff + 1024 * j + k1);
      __builtin_amdgcn_sched_barrier(0);
      __builtin_amdgcn_s_setprio(1);
#pragma unroll
      for (int i = 0; i < 4; ++i)
#pragma unroll
        for (int j = 0; j < 8; ++j)
          acc[i][j] = mfma16(a[i], b[j], acc[i][j]);
      __builtin_amdgcn_s_setprio(0);
    }
    __syncthreads();
    if (++kw == 7) { kw = 0; ++kh; }
  }

  // epilogue: relu, write y2 NHWC bf16 (active rows only)
  // M row = wave*64 + 16i + 4*kg + r -> cellslot = wave*16 + 4i + kg, p = r.
#pragma unroll
  for (int i = 0; i < 4; ++i) {
    int cellslot = wave * 16 + 4 * i + kg;
    int cellidx = mt * 64 + cellslot;
    if (cellidx >= cnt) continue;
    int cell = scs[cellslot];
    int b = cell / 196, cc = cell - b * 196;
    int ci = cc / 14, cj = cc - ci * 14;
#pragma unroll
    for (int j = 0; j < 8; ++j) {
      int oc = ocb + 16 * j + mrow;
#pragma unroll
      for (int r = 0; r < 4; ++r) {
        int oh = 2 * ci + (r >> 1), ow = 2 * cj + (r & 1);
        float v = acc[i][j][r];
        v = v > 0.f ? v : 0.f;
        y2[(((size_t)(b * 784)) + oh * 28 + ow) * 768 + oc] = f2bf(v);
      }
    }
  }
}

// ---------------- stage 6: MaxBlurPool2 (28 -> 14) + transpose to [B,196,768] fp32 ----------------
__global__ __launch_bounds__(256) void k_pool2(const uint16_t* __restrict__ y2, const int* __restrict__ masks,
                                               float* __restrict__ out) {
  __shared__ uint16_t sY[4 * 28 * 128];   // 28,672 B
  int chunk = blockIdx.x, pi = blockIdx.y, b = blockIdx.z;
  int ch0 = chunk * 128;
  int tid = threadIdx.x;
  const int* mb = masks + b * 196;

  for (int idx = tid; idx < 1792; idx += 256) {
    int rc = idx >> 4;
    int sub = idx & 15;
    int k = rc / 28, c = rc - k * 28;
    int r = 2 * pi - 1 + k;
    short8 v = {0, 0, 0, 0, 0, 0, 0, 0};
    if ((unsigned)r < 28u && mb[(r >> 1) * 14 + (c >> 1)])
      v = *(const short8*)(y2 + (((size_t)(b * 784)) + r * 28 + c) * 768 + ch0 + sub * 8);
    *(short8*)(sY + ((size_t)(k * 28 + c)) * 128 + sub * 8) = v;
  }
  __syncthreads();

  for (int idx = tid; idx < 1792; idx += 256) {
    int pj = idx >> 7, ch = idx & 127;
    float v[4][4];
#pragma unroll
    for (int e = 0; e < 4; ++e) {
      int col = 2 * pj - 1 + e;
      bool cv = (unsigned)col < 28u;
#pragma unroll
      for (int k = 0; k < 4; ++k)
        v[k][e] = cv ? bf2f(sY[((size_t)(k * 28 + col)) * 128 + ch]) : 0.f;
    }
    float acc = 0.f;
#pragma unroll
    for (int d = 0; d < 3; ++d) {
      int q = 2 * pi - 1 + d;
      float gd = ((unsigned)q <= 26u) ? ((d == 1) ? 2.f : 1.f) : 0.f;
      float s = 0.f;
#pragma unroll
      for (int e = 0; e < 3; ++e) {
        int q2 = 2 * pj - 1 + e;
        float ge = ((unsigned)q2 <= 26u) ? ((e == 1) ? 2.f : 1.f) : 0.f;
        float m = fmaxf(fmaxf(v[d][e], v[d + 1][e]), fmaxf(v[d][e + 1], v[d + 1][e + 1]));
        s += ge * m;
      }
      acc += gd * s;
    }
    out[(((size_t)(b * 196)) + pi * 14 + pj) * 768 + ch0 + ch] = acc * (1.f / 16.f);
  }
}

// ---------------- launcher ----------------
extern "C" void kernel_launch(void* const* d_in, const int* in_sizes, int n_in,
                              void* d_out, int out_size, void* d_ws, size_t ws_size,
                              hipStream_t stream) {
  const float* x     = (const float*)d_in[0];
  const int*   masks = (const int*)d_in[1];
  const float* w1    = (const float*)d_in[2];
  const float* w2    = (const float*)d_in[3];

  char* ws = (char*)d_ws;
  if (ws_size < WS_NEED) return;

  uint16_t* xp  = (uint16_t*)(ws + OFF_XP);
  uint16_t* w1t = (uint16_t*)(ws + OFF_W1T);
  uint16_t* w2t = (uint16_t*)(ws + OFF_W2T);
  uint16_t* y1  = (uint16_t*)(ws + OFF_Y1);
  uint16_t* p1  = (uint16_t*)(ws + OFF_P1);
  uint16_t* y2  = (uint16_t*)(ws + OFF_Y2);
  int* list     = (int*)(ws + OFF_LIST);
  int* cnts     = (int*)(ws + OFF_CNT);
  int* total    = cnts + 49;

  k_count<<<49, 256, 0, stream>>>(masks, cnts);
  k_emit<<<49, 256, 0, stream>>>(masks, cnts, list, total);
  k_prep<<<13456, 256, 0, stream>>>(x, masks, xp);
  k_wt<<<9464, 256, 0, stream>>>(w1, w2, w1t, w2t);
  k_conv1<<<6272, 256, 0, stream>>>(xp, w1t, list, total, y1);
  k_pool1<<<dim3(64, 64), 256, 0, stream>>>(y1, masks, p1);
  // 8 XCDs x 25 mt-slots x 6 oc-slices = 1200 blocks (M=256 tiles, 64 cells each); 6 slices of an
  // mt are consecutive same-XCD ids (gx = xcd + 8*(mtl*6 + y)) for A-tile L2 reuse.
  k_conv2<<<1200, 256, 0, stream>>>(p1, w2t, list, total, y2);
  k_pool2<<<dim3(6, 14, 64), 256, 0, stream>>>(y2, masks, (float*)d_out);
}

// Round 9
// 354.573 us; speedup vs baseline: 1.0866x; 1.0866x over previous
//
#include <hip/hip_runtime.h>
#include <stdint.h>

typedef __attribute__((ext_vector_type(8))) short short8;
typedef __attribute__((ext_vector_type(4))) float f32x4;

#define DEVFN static __device__ __forceinline__

// ---------------- helpers ----------------
DEVFN float bf2f(uint16_t u) { union { uint32_t i; float f; } v; v.i = ((uint32_t)u) << 16; return v.f; }
DEVFN uint16_t f2bf(float f) {
  union { float f; uint32_t i; } v; v.f = f;
  uint32_t u = v.i;
  u += 0x7fffu + ((u >> 16) & 1u);   // RNE
  return (uint16_t)(u >> 16);
}
DEVFN int imin(int a, int b) { return a < b ? a : b; }

DEVFN void gl_lds16(const void* g, void* l) {
  __builtin_amdgcn_global_load_lds(
      (__attribute__((address_space(1))) void*)(void*)g,
      (__attribute__((address_space(3))) void*)l, 16, 0, 0);
}

DEVFN f32x4 mfma16(short8 a, short8 b, f32x4 c) {
  return __builtin_amdgcn_mfma_f32_16x16x32_bf16(a, b, c, 0, 0, 0);
}

// ---------------- workspace layout (bytes) ----------------
static constexpr size_t OFF_XP   = 0;          // bf16 [64][232][232][4]  x: masked, padded(+3), NHWC4
static constexpr size_t OFF_W1T  = 27557888;   // bf16 [7][64][32]        w1t[kh][oc][kw*4+ic]
static constexpr size_t OFF_W2T  = 27586560;   // bf16 [49][768][64]      w2t[kh*7+kw][oc][ic]
static constexpr size_t OFF_Y1   = 32403456;   // bf16 [64][112][112][64] conv1 out (active cells only)
static constexpr size_t OFF_P1   = 135163904;  // bf16 [64][62][62][64]   pool1 out, padded(+3), NHWC
static constexpr size_t OFF_Y2   = 166653952;  // bf16 [64][28][28][768]  conv2 out (active cells only)
static constexpr size_t OFF_LIST = 243724288;  // int [12544] active cell list, SORTED
static constexpr size_t OFF_CNT  = 243774464;  // int cnts[49] + int total
static constexpr size_t WS_NEED  = 243774664;

// ---------------- stage 0a: per-block mask counts ----------------
__global__ __launch_bounds__(256) void k_count(const int* __restrict__ masks, int* __restrict__ cnts) {
  int b = blockIdx.x;
  int gid = b * 256 + threadIdx.x;   // 49*256 = 12544 exactly
  unsigned long long m = __ballot(masks[gid] != 0);
  __shared__ int wsum[4];
  if ((threadIdx.x & 63) == 0) wsum[threadIdx.x >> 6] = __popcll(m);
  __syncthreads();
  if (threadIdx.x == 0) cnts[b] = wsum[0] + wsum[1] + wsum[2] + wsum[3];
}

// ---------------- stage 0b: deterministic sorted compaction ----------------
__global__ __launch_bounds__(256) void k_emit(const int* __restrict__ masks, const int* __restrict__ cnts,
                                              int* __restrict__ list, int* __restrict__ total) {
  int b = blockIdx.x;
  int gid = b * 256 + threadIdx.x;
  int lane = threadIdx.x & 63, wave = threadIdx.x >> 6;
  int base = 0;
  for (int i = 0; i < b; ++i) base += cnts[i];
  bool f = masks[gid] != 0;
  unsigned long long m = __ballot(f);
  __shared__ int wcnt[4];
  if (lane == 0) wcnt[wave] = __popcll(m);
  __syncthreads();
  int woff = 0;
  for (int i = 0; i < wave; ++i) woff += wcnt[i];
  if (f) list[base + woff + __popcll(m & ((1ull << lane) - 1ull))] = gid;
  if (b == 48 && threadIdx.x == 0)
    *total = base + wcnt[0] + wcnt[1] + wcnt[2] + wcnt[3];
}

// ---------------- stage 1: x -> masked bf16 NHWC4 padded ----------------
__global__ __launch_bounds__(256) void k_prep(const float* __restrict__ x, const int* __restrict__ masks,
                                              uint16_t* __restrict__ xp) {
  int gid = blockIdx.x * 256 + threadIdx.x;   // 64*232*232 = 3,444,736 exactly
  int b = gid / 53824;
  int rc = gid - b * 53824;
  int r2 = rc / 232;
  int c2 = rc - r2 * 232;
  int r = r2 - 3, c = c2 - 3;
  uint16_t o0 = 0, o1 = 0, o2 = 0;
  if ((unsigned)r < 224u && (unsigned)c < 224u) {
    if (masks[b * 196 + (r >> 4) * 14 + (c >> 4)]) {
      const float* px = x + (((size_t)b * 3) * 224 + r) * 224 + c;
      o0 = f2bf(px[0]);
      o1 = f2bf(px[50176]);
      o2 = f2bf(px[100352]);
    }
  }
  ushort4 o; o.x = o0; o.y = o1; o.z = o2; o.w = 0;
  *(ushort4*)(xp + (size_t)gid * 4) = o;
}

// ---------------- stage 2: weight transforms ----------------
__global__ __launch_bounds__(256) void k_wt(const float* __restrict__ w1, const float* __restrict__ w2,
                                            uint16_t* __restrict__ w1t, uint16_t* __restrict__ w2t) {
  int gid = blockIdx.x * 256 + threadIdx.x;   // 14336 + 2408448 = 2,422,784 exactly
  if (gid < 14336) {
    int kh = gid / 2048; int r = gid - kh * 2048;
    int oc = r >> 5, slot = r & 31;
    int kw = slot >> 2, ic = slot & 3;
    float v = 0.f;
    if (kw < 7 && ic < 3) v = w1[((oc * 3 + ic) * 7 + kh) * 7 + kw];
    w1t[gid] = f2bf(v);
  } else {
    int g2 = gid - 14336;
    int khw = g2 / 49152; int r = g2 - khw * 49152;
    int oc = r >> 6, ic = r & 63;
    int kh = khw / 7, kw = khw - kh * 7;
    w2t[g2] = f2bf(w2[((oc * 64 + ic) * 7 + kh) * 7 + kw]);
  }
}

// ---------------- stage 3: conv1 (7x7 s2) — barrier-free K-loop ----------------
__global__ __launch_bounds__(256, 3) void k_conv1(const uint16_t* __restrict__ xp, const uint16_t* __restrict__ w1t,
                                                  const int* __restrict__ list, const int* __restrict__ count,
                                                  uint16_t* __restrict__ y1) {
  __shared__ uint16_t sB[7 * 64 * 32];   // 28 KB: whole w1t resident
  __shared__ int sc[2];

  int cnt = *count;
  int blk = blockIdx.x;
  if (blk * 2 >= cnt) return;
  int tid = threadIdx.x, lane = tid & 63, wave = tid >> 6;
  int csw = (lane & 3) ^ ((lane >> 2) & 3);

  {
    const char* wg = (const char*)w1t;
    char* wl = (char*)sB;
#pragma unroll
    for (int t = 0; t < 7; ++t) {
      int ldsoff = t * 4096 + wave * 1024;
      int goff = t * 4096 + (wave * 16 + (lane >> 2)) * 64 + csw * 16;
      gl_lds16(wg + goff, wl + ldsoff);
    }
  }
  if (tid < 2) sc[tid] = list[imin(blk * 2 + tid, cnt - 1)];
  __syncthreads();

  int wm = wave * 32, mrow = lane & 15, kg = lane >> 4;

  const uint16_t* baseA[2];
#pragma unroll
  for (int i = 0; i < 2; ++i) {
    int row = wm + 16 * i + mrow;
    int cell = sc[row >> 6];
    int b = cell / 196, cc = cell - b * 196;
    int ci = cc / 14, cj = cc - ci * 14;
    int p = row & 63;
    int oh = ci * 8 + (p >> 3), ow = cj * 8 + (p & 7);
    baseA[i] = xp + (((size_t)(b * 232 + 2 * oh)) * 232 + 2 * ow) * 4 + kg * 8;
  }
  int ksw = (kg ^ (mrow & 3)) * 8;

  f32x4 acc[2][4];
#pragma unroll
  for (int i = 0; i < 2; ++i)
#pragma unroll
    for (int j = 0; j < 4; ++j) acc[i][j] = f32x4{0.f, 0.f, 0.f, 0.f};

#pragma unroll
  for (int kh = 0; kh < 7; ++kh) {
    short8 a0 = *(const short8*)(baseA[0] + kh * 928);
    short8 a1 = *(const short8*)(baseA[1] + kh * 928);
    const uint16_t* Bk = sB + kh * 2048;
#pragma unroll
    for (int j = 0; j < 4; ++j) {
      short8 bj = *(const short8*)(Bk + (16 * j + mrow) * 32 + ksw);
      acc[0][j] = mfma16(a0, bj, acc[0][j]);
      acc[1][j] = mfma16(a1, bj, acc[1][j]);
    }
  }

#pragma unroll
  for (int i = 0; i < 2; ++i) {
    int rbase = wm + 16 * i;
    int cellidx = blk * 2 + (rbase >> 6);
    if (cellidx >= cnt) continue;
    int cell = sc[rbase >> 6];
    int b = cell / 196, cc = cell - b * 196;
    int ci = cc / 14, cj = cc - ci * 14;
#pragma unroll
    for (int j = 0; j < 4; ++j) {
      int oc = 16 * j + mrow;
#pragma unroll
      for (int r = 0; r < 4; ++r) {
        int row = rbase + kg * 4 + r;
        int p = row & 63;
        int oh = ci * 8 + (p >> 3), ow = cj * 8 + (p & 7);
        float v = acc[i][j][r];
        v = v > 0.f ? v : 0.f;
        y1[(((size_t)(b * 112 + oh)) * 112 + ow) * 64 + oc] = f2bf(v);
      }
    }
  }
}

// ---------------- stage 4: MaxBlurPool1 (112 -> 56), mask-aware, writes padded p1 ----------------
__global__ __launch_bounds__(256) void k_pool1(const uint16_t* __restrict__ y1, const int* __restrict__ masks,
                                               uint16_t* __restrict__ p1) {
  __shared__ uint16_t sY[18 * 18 * 64];  // 41,472 B
  int b = blockIdx.y;
  int tile = blockIdx.x;
  int tr = tile >> 3, tc = tile & 7;
  int pr0 = tr * 8, pc0 = tc * 8;
  int R0 = 2 * pr0 - 7, C0 = 2 * pc0 - 7;
  int tid = threadIdx.x;
  const int* mb = masks + b * 196;

  for (int idx = tid; idx < 2592; idx += 256) {
    int pix = idx >> 3, ch = idx & 7;
    int pr = pix / 18, pc = pix - pr * 18;
    int r = R0 + pr, c = C0 + pc;
    short8 v = {0, 0, 0, 0, 0, 0, 0, 0};
    if ((unsigned)r < 112u && (unsigned)c < 112u && mb[(r >> 3) * 14 + (c >> 3)])
      v = *(const short8*)(y1 + (((size_t)(b * 112 + r)) * 112 + c) * 64 + ch * 8);
    *(short8*)(sY + ((size_t)(pr * 18 + pc)) * 64 + ch * 8) = v;
  }
  __syncthreads();

  for (int it = tid; it < 512; it += 256) {
    int opix = it >> 3, ch = it & 7;
    int lr = opix >> 3, lc = opix & 7;
    int pr = pr0 + lr, pc = pc0 + lc;
    if (pr >= 62 || pc >= 62) continue;
    int oh = pr - 3, ow = pc - 3;
    float acc[8] = {0.f, 0.f, 0.f, 0.f, 0.f, 0.f, 0.f, 0.f};
    if ((unsigned)oh < 56u && (unsigned)ow < 56u) {
      float hm_prev[3][8];
#pragma unroll
      for (int dd = 0; dd < 4; ++dd) {
        float yv[4][8];
        const uint16_t* src = sY + ((size_t)((2 * lr + dd) * 18 + 2 * lc)) * 64 + ch * 8;
#pragma unroll
        for (int e = 0; e < 4; ++e) {
          short8 t8 = *(const short8*)(src + e * 64);
#pragma unroll
          for (int k = 0; k < 8; ++k) yv[e][k] = bf2f((uint16_t)t8[k]);
        }
        float hm[3][8];
#pragma unroll
        for (int e = 0; e < 3; ++e) {
          int qc = 2 * ow - 1 + e;
          float cv = ((unsigned)qc <= 110u) ? 1.f : 0.f;
#pragma unroll
          for (int k = 0; k < 8; ++k) hm[e][k] = cv * fmaxf(yv[e][k], yv[e + 1][k]);
        }
        if (dd > 0) {
          int d = dd - 1;
          int qr = 2 * oh - 1 + d;
          if ((unsigned)qr <= 110u) {
            float wd = (d == 1) ? 2.f : 1.f;
#pragma unroll
            for (int e = 0; e < 3; ++e) {
              float w = wd * ((e == 1) ? 2.f : 1.f);
#pragma unroll
              for (int k = 0; k < 8; ++k) acc[k] += w * fmaxf(hm_prev[e][k], hm[e][k]);
            }
          }
        }
#pragma unroll
        for (int e = 0; e < 3; ++e)
#pragma unroll
          for (int k = 0; k < 8; ++k) hm_prev[e][k] = hm[e][k];
      }
#pragma unroll
      for (int k = 0; k < 8; ++k) acc[k] *= (1.f / 16.f);
    }
    short8 o;
#pragma unroll
    for (int k = 0; k < 8; ++k) o[k] = (short)f2bf(acc[k]);
    *(short8*)(p1 + (((size_t)(b * 62 + pr)) * 62 + pc) * 64 + ch * 8) = o;
  }
}

// ---------------- stage 5: conv2 (7x7 s2) — MFMA 128x128, 4 waves, 2-barrier, piped ks ----------
// R9 = R6 verbatim (measured best: 122.4us, MfmaUtil 46%, VGPR 80, no spill). Session-verified
// coupling: 128^2 tile (2352 blocks -> 9.2/CU packing) + ALL-16-ds_reads-up-front (ks1 burst
// overlaps ks0 MFMA; needs <=16 live frags -> N=64/wave) + (256,3) VGPR headroom. Alternatives
// all regressed on HW: M=256 serial-ks (R8 -26%), dbuf 64KB (R7 -13%), dbuf 96KB (R1 -8%),
// direct-reg A (R2 -2.6x), (256,5) spill (R4 -80%). Residual = barrier-locked stage drain;
// only the full 8-phase 256^2 template removes it, and its packing (294 blocks, 1/CU) cannot
// win at this problem size.
__global__ __launch_bounds__(256, 3) void k_conv2(const uint16_t* __restrict__ p1, const uint16_t* __restrict__ w2t,
                                                  const int* __restrict__ list, const int* __restrict__ count,
                                                  uint16_t* __restrict__ y2) {
  __shared__ uint16_t sA[128 * 64];   // 16 KB  A[row][ic]
  __shared__ uint16_t sBt[128 * 64];  // 16 KB  B^T[oc][ic]
  __shared__ int scs[32];

  int cnt = *count;
  int gx = blockIdx.x;
  int xcd = gx & 7, s = gx >> 3;
  int y = s % 6, mtl = s / 6;
  int mt = xcd + 8 * mtl;            // 0..391
  if (mt * 32 >= cnt) return;
  int ocb = y * 128;
  int tid = threadIdx.x, lane = tid & 63, wave = tid >> 6;   // 4 waves
  int csw = (lane & 7) ^ ((lane >> 3) & 7);

  if (tid < 32) scs[tid] = list[imin(mt * 32 + tid, cnt - 1)];
  __syncthreads();

  int qm = wave & 1, qn = wave >> 1;
  int mrow = lane & 15, kg = lane >> 4;

  // A staging: rows r = wave*32 + t*8 + (lane>>3), t=0..3 -> 128 rows; chunk csw pre-swizzled.
  const char* gA[4];
#pragma unroll
  for (int t = 0; t < 4; ++t) {
    int r = wave * 32 + t * 8 + (lane >> 3);
    int cell = scs[r >> 2];
    int b = cell / 196, cc = cell - b * 196;
    int ci = cc / 14, cj = cc - ci * 14;
    int p = r & 3;
    int oh = 2 * ci + (p >> 1), ow = 2 * cj + (p & 1);
    gA[t] = (const char*)p1 + (((size_t)(b * 62 + 2 * oh)) * 62 + 2 * ow) * 128 + csw * 16;
  }
  // B staging: oc rows wave*32 + t*8 + (lane>>3), t=0..3 -> 128 oc.
  const char* gB[4];
#pragma unroll
  for (int t = 0; t < 4; ++t) {
    int oc = ocb + wave * 32 + t * 8 + (lane >> 3);
    gB[t] = (const char*)w2t + (size_t)oc * 128 + csw * 16;
  }

  f32x4 acc[4][4];
#pragma unroll
  for (int i = 0; i < 4; ++i)
#pragma unroll
    for (int j = 0; j < 4; ++j) acc[i][j] = f32x4{0.f, 0.f, 0.f, 0.f};

  int sw8 = mrow & 7;
  int kh = 0, kw = 0;
  char* la = (char*)sA + wave * 4096;
  char* lb = (char*)sBt + wave * 4096;
  int k0 = (kg ^ sw8) * 8;          // ks=0 chunk offset (elems)
  int k1 = ((4 + kg) ^ sw8) * 8;    // ks=1 chunk offset

#pragma unroll 1
  for (int it = 0; it < 49; ++it) {
    size_t offA = (size_t)(kh * 62 + kw) * 128;
    size_t offB = (size_t)it * 98304;   // 768*64 elems * 2 B per tap
#pragma unroll
    for (int t = 0; t < 4; ++t) gl_lds16(gA[t] + offA, la + t * 1024);
#pragma unroll
    for (int t = 0; t < 4; ++t) gl_lds16(gB[t] + offB, lb + t * 1024);
    __syncthreads();
    // issue ALL 16 ds_reads (both k-slices) before any MFMA
    short8 a0[4], b0[4], a1[4], b1[4];
#pragma unroll
    for (int i = 0; i < 4; ++i)
      a0[i] = *(const short8*)(sA + (qm * 64 + 16 * i + mrow) * 64 + k0);
#pragma unroll
    for (int j = 0; j < 4; ++j)
      b0[j] = *(const short8*)(sBt + (qn * 64 + 16 * j + mrow) * 64 + k0);
#pragma unroll
    for (int i = 0; i < 4; ++i)
      a1[i] = *(const short8*)(sA + (qm * 64 + 16 * i + mrow) * 64 + k1);
#pragma unroll
    for (int j = 0; j < 4; ++j)
      b1[j] = *(const short8*)(sBt + (qn * 64 + 16 * j + mrow) * 64 + k1);
    __builtin_amdgcn_sched_barrier(0);   // all reads issued; nothing sinks below
    __builtin_amdgcn_s_setprio(1);
#pragma unroll
    for (int i = 0; i < 4; ++i)
#pragma unroll
      for (int j = 0; j < 4; ++j)
        acc[i][j] = mfma16(a0[i], b0[j], acc[i][j]);   // waits only ks0's 8 reads
    __builtin_amdgcn_s_setprio(0);
    __builtin_amdgcn_sched_barrier(0);
    __builtin_amdgcn_s_setprio(1);
#pragma unroll
    for (int i = 0; i < 4; ++i)
#pragma unroll
      for (int j = 0; j < 4; ++j)
        acc[i][j] = mfma16(a1[i], b1[j], acc[i][j]);
    __builtin_amdgcn_s_setprio(0);
    __syncthreads();
    if (++kw == 7) { kw = 0; ++kh; }
  }

  // epilogue: relu, write y2 NHWC bf16 (active rows only)
#pragma unroll
  for (int i = 0; i < 4; ++i) {
    int cellslot = qm * 16 + 4 * i + kg;
    int cellidx = mt * 32 + cellslot;
    if (cellidx >= cnt) continue;
    int cell = scs[cellslot];
    int b = cell / 196, cc = cell - b * 196;
    int ci = cc / 14, cj = cc - ci * 14;
#pragma unroll
    for (int j = 0; j < 4; ++j) {
      int oc = ocb + qn * 64 + 16 * j + mrow;
#pragma unroll
      for (int r = 0; r < 4; ++r) {
        int oh = 2 * ci + (r >> 1), ow = 2 * cj + (r & 1);
        float v = acc[i][j][r];
        v = v > 0.f ? v : 0.f;
        y2[(((size_t)(b * 784)) + oh * 28 + ow) * 768 + oc] = f2bf(v);
      }
    }
  }
}

// ---------------- stage 6: MaxBlurPool2 (28 -> 14) + transpose to [B,196,768] fp32 ----------------
__global__ __launch_bounds__(256) void k_pool2(const uint16_t* __restrict__ y2, const int* __restrict__ masks,
                                               float* __restrict__ out) {
  __shared__ uint16_t sY[4 * 28 * 128];   // 28,672 B
  int chunk = blockIdx.x, pi = blockIdx.y, b = blockIdx.z;
  int ch0 = chunk * 128;
  int tid = threadIdx.x;
  const int* mb = masks + b * 196;

  for (int idx = tid; idx < 1792; idx += 256) {
    int rc = idx >> 4;
    int sub = idx & 15;
    int k = rc / 28, c = rc - k * 28;
    int r = 2 * pi - 1 + k;
    short8 v = {0, 0, 0, 0, 0, 0, 0, 0};
    if ((unsigned)r < 28u && mb[(r >> 1) * 14 + (c >> 1)])
      v = *(const short8*)(y2 + (((size_t)(b * 784)) + r * 28 + c) * 768 + ch0 + sub * 8);
    *(short8*)(sY + ((size_t)(k * 28 + c)) * 128 + sub * 8) = v;
  }
  __syncthreads();

  for (int idx = tid; idx < 1792; idx += 256) {
    int pj = idx >> 7, ch = idx & 127;
    float v[4][4];
#pragma unroll
    for (int e = 0; e < 4; ++e) {
      int col = 2 * pj - 1 + e;
      bool cv = (unsigned)col < 28u;
#pragma unroll
      for (int k = 0; k < 4; ++k)
        v[k][e] = cv ? bf2f(sY[((size_t)(k * 28 + col)) * 128 + ch]) : 0.f;
    }
    float acc = 0.f;
#pragma unroll
    for (int d = 0; d < 3; ++d) {
      int q = 2 * pi - 1 + d;
      float gd = ((unsigned)q <= 26u) ? ((d == 1) ? 2.f : 1.f) : 0.f;
      float s = 0.f;
#pragma unroll
      for (int e = 0; e < 3; ++e) {
        int q2 = 2 * pj - 1 + e;
        float ge = ((unsigned)q2 <= 26u) ? ((e == 1) ? 2.f : 1.f) : 0.f;
        float m = fmaxf(fmaxf(v[d][e], v[d + 1][e]), fmaxf(v[d][e + 1], v[d + 1][e + 1]));
        s += ge * m;
      }
      acc += gd * s;
    }
    out[(((size_t)(b * 196)) + pi * 14 + pj) * 768 + ch0 + ch] = acc * (1.f / 16.f);
  }
}

// ---------------- launcher ----------------
extern "C" void kernel_launch(void* const* d_in, const int* in_sizes, int n_in,
                              void* d_out, int out_size, void* d_ws, size_t ws_size,
                              hipStream_t stream) {
  const float* x     = (const float*)d_in[0];
  const int*   masks = (const int*)d_in[1];
  const float* w1    = (const float*)d_in[2];
  const float* w2    = (const float*)d_in[3];

  char* ws = (char*)d_ws;
  if (ws_size < WS_NEED) return;

  uint16_t* xp  = (uint16_t*)(ws + OFF_XP);
  uint16_t* w1t = (uint16_t*)(ws + OFF_W1T);
  uint16_t* w2t = (uint16_t*)(ws + OFF_W2T);
  uint16_t* y1  = (uint16_t*)(ws + OFF_Y1);
  uint16_t* p1  = (uint16_t*)(ws + OFF_P1);
  uint16_t* y2  = (uint16_t*)(ws + OFF_Y2);
  int* list     = (int*)(ws + OFF_LIST);
  int* cnts     = (int*)(ws + OFF_CNT);
  int* total    = cnts + 49;

  k_count<<<49, 256, 0, stream>>>(masks, cnts);
  k_emit<<<49, 256, 0, stream>>>(masks, cnts, list, total);
  k_prep<<<13456, 256, 0, stream>>>(x, masks, xp);
  k_wt<<<9464, 256, 0, stream>>>(w1, w2, w1t, w2t);
  k_conv1<<<6272, 256, 0, stream>>>(xp, w1t, list, total, y1);
  k_pool1<<<dim3(64, 64), 256, 0, stream>>>(y1, masks, p1);
  // 8 XCDs x 49 mt-slots x 6 oc-slices = 2352 blocks (M=128 tiles); 6 slices of an mt are
  // consecutive same-XCD ids (gx = xcd + 8*(mtl*6 + y)) for A-tile L2 reuse.
  k_conv2<<<2352, 256, 0, stream>>>(p1, w2t, list, total, y2);
  k_pool2<<<dim3(6, 14, 64), 256, 0, stream>>>(y2, masks, (float*)d_out);
}

// Round 11
// 353.853 us; speedup vs baseline: 1.0888x; 1.0020x over previous
//
#include <hip/hip_runtime.h>
#include <stdint.h>

typedef __attribute__((ext_vector_type(8))) short short8;
typedef __attribute__((ext_vector_type(4))) float f32x4;

#define DEVFN static __device__ __forceinline__

// ---------------- helpers ----------------
DEVFN float bf2f(uint16_t u) { union { uint32_t i; float f; } v; v.i = ((uint32_t)u) << 16; return v.f; }
DEVFN uint16_t f2bf(float f) {
  union { float f; uint32_t i; } v; v.f = f;
  uint32_t u = v.i;
  u += 0x7fffu + ((u >> 16) & 1u);   // RNE
  return (uint16_t)(u >> 16);
}
DEVFN int imin(int a, int b) { return a < b ? a : b; }

DEVFN void gl_lds16(const void* g, void* l) {
  __builtin_amdgcn_global_load_lds(
      (__attribute__((address_space(1))) void*)(void*)g,
      (__attribute__((address_space(3))) void*)l, 16, 0, 0);
}

DEVFN f32x4 mfma16(short8 a, short8 b, f32x4 c) {
  return __builtin_amdgcn_mfma_f32_16x16x32_bf16(a, b, c, 0, 0, 0);
}

// ---------------- workspace layout (bytes) ----------------
static constexpr size_t OFF_XP   = 0;          // bf16 [64][232][232][4]  x: masked, padded(+3), NHWC4
static constexpr size_t OFF_W1T  = 27557888;   // bf16 [7][64][32]        w1t[kh][oc][kw*4+ic]
static constexpr size_t OFF_W2T  = 27586560;   // bf16 [49][768][64]      w2t[kh*7+kw][oc][ic]
static constexpr size_t OFF_Y1   = 32403456;   // bf16 [64][112][112][64] conv1 out (active cells only)
static constexpr size_t OFF_P1   = 135163904;  // bf16 [64][62][62][64]   pool1 out, padded(+3), NHWC
static constexpr size_t OFF_Y2   = 166653952;  // bf16 [64][28][28][768]  conv2 out (active cells only)
static constexpr size_t OFF_LIST = 243724288;  // int [12544] active cell list, SORTED
static constexpr size_t OFF_CNT  = 243774464;  // int cnts[49] + int total
static constexpr size_t WS_NEED  = 243774664;

// ---------------- stage 0+1+2 fused front end ----------------
// R11 = R10 resubmit (R10 bench was an infra failure, no data; R5 precedent: identical resubmit
// validated). One dispatch replaces k_count+k_emit+k_prep+k_wt (8 launches -> 5 total).
// Block 0: single-block deterministic sorted compaction (49 rounds, running prefix in LDS)
//          — removes the per-block O(b) serial global prefix loop of the old k_emit.
// Blocks 1..13456: x -> masked bf16 NHWC4 padded (old k_prep, gid shifted).
// Blocks 13457..22920: weight transforms (old k_wt, gid shifted).
// No inter-branch dependencies; emit's ~6us on one CU hides under prep/wt.
__global__ __launch_bounds__(256) void k_front(const int* __restrict__ masks, const float* __restrict__ x,
                                               const float* __restrict__ w1, const float* __restrict__ w2,
                                               int* __restrict__ list, int* __restrict__ total,
                                               uint16_t* __restrict__ xp, uint16_t* __restrict__ w1t,
                                               uint16_t* __restrict__ w2t) {
  int bid = blockIdx.x;
  int tid = threadIdx.x;
  if (bid == 0) {
    __shared__ int sbase;
    __shared__ int wc[4];
    int lane = tid & 63, wave = tid >> 6;
    if (tid == 0) sbase = 0;
    __syncthreads();
#pragma unroll 1
    for (int r = 0; r < 49; ++r) {
      int gid = r * 256 + tid;
      bool f = masks[gid] != 0;
      unsigned long long m = __ballot(f);
      if (lane == 0) wc[wave] = __popcll(m);
      __syncthreads();
      int b0 = sbase;
      int woff = 0;
      for (int i = 0; i < wave; ++i) woff += wc[i];
      if (f) list[b0 + woff + __popcll(m & ((1ull << lane) - 1ull))] = gid;
      int rt = wc[0] + wc[1] + wc[2] + wc[3];
      __syncthreads();
      if (tid == 0) sbase = b0 + rt;
    }
    __syncthreads();
    if (tid == 0) *total = sbase;
  } else if (bid <= 13456) {
    int gid = (bid - 1) * 256 + tid;   // 64*232*232 = 3,444,736 exactly
    int b = gid / 53824;
    int rc = gid - b * 53824;
    int r2 = rc / 232;
    int c2 = rc - r2 * 232;
    int r = r2 - 3, c = c2 - 3;
    uint16_t o0 = 0, o1 = 0, o2 = 0;
    if ((unsigned)r < 224u && (unsigned)c < 224u) {
      if (masks[b * 196 + (r >> 4) * 14 + (c >> 4)]) {
        const float* px = x + (((size_t)b * 3) * 224 + r) * 224 + c;
        o0 = f2bf(px[0]);
        o1 = f2bf(px[50176]);
        o2 = f2bf(px[100352]);
      }
    }
    ushort4 o; o.x = o0; o.y = o1; o.z = o2; o.w = 0;
    *(ushort4*)(xp + (size_t)gid * 4) = o;
  } else {
    int gid = (bid - 13457) * 256 + tid;   // 14336 + 2408448 = 2,422,784 exactly
    if (gid < 14336) {
      int kh = gid / 2048; int r = gid - kh * 2048;
      int oc = r >> 5, slot = r & 31;
      int kw = slot >> 2, ic = slot & 3;
      float v = 0.f;
      if (kw < 7 && ic < 3) v = w1[((oc * 3 + ic) * 7 + kh) * 7 + kw];
      w1t[gid] = f2bf(v);
    } else {
      int g2 = gid - 14336;
      int khw = g2 / 49152; int r = g2 - khw * 49152;
      int oc = r >> 6, ic = r & 63;
      int kh = khw / 7, kw = khw - kh * 7;
      w2t[g2] = f2bf(w2[((oc * 64 + ic) * 7 + kh) * 7 + kw]);
    }
  }
}

// ---------------- stage 3: conv1 (7x7 s2) — barrier-free K-loop ----------------
__global__ __launch_bounds__(256, 3) void k_conv1(const uint16_t* __restrict__ xp, const uint16_t* __restrict__ w1t,
                                                  const int* __restrict__ list, const int* __restrict__ count,
                                                  uint16_t* __restrict__ y1) {
  __shared__ uint16_t sB[7 * 64 * 32];   // 28 KB: whole w1t resident
  __shared__ int sc[2];

  int cnt = *count;
  int blk = blockIdx.x;
  if (blk * 2 >= cnt) return;
  int tid = threadIdx.x, lane = tid & 63, wave = tid >> 6;
  int csw = (lane & 3) ^ ((lane >> 2) & 3);

  {
    const char* wg = (const char*)w1t;
    char* wl = (char*)sB;
#pragma unroll
    for (int t = 0; t < 7; ++t) {
      int ldsoff = t * 4096 + wave * 1024;
      int goff = t * 4096 + (wave * 16 + (lane >> 2)) * 64 + csw * 16;
      gl_lds16(wg + goff, wl + ldsoff);
    }
  }
  if (tid < 2) sc[tid] = list[imin(blk * 2 + tid, cnt - 1)];
  __syncthreads();

  int wm = wave * 32, mrow = lane & 15, kg = lane >> 4;

  const uint16_t* baseA[2];
#pragma unroll
  for (int i = 0; i < 2; ++i) {
    int row = wm + 16 * i + mrow;
    int cell = sc[row >> 6];
    int b = cell / 196, cc = cell - b * 196;
    int ci = cc / 14, cj = cc - ci * 14;
    int p = row & 63;
    int oh = ci * 8 + (p >> 3), ow = cj * 8 + (p & 7);
    baseA[i] = xp + (((size_t)(b * 232 + 2 * oh)) * 232 + 2 * ow) * 4 + kg * 8;
  }
  int ksw = (kg ^ (mrow & 3)) * 8;

  f32x4 acc[2][4];
#pragma unroll
  for (int i = 0; i < 2; ++i)
#pragma unroll
    for (int j = 0; j < 4; ++j) acc[i][j] = f32x4{0.f, 0.f, 0.f, 0.f};

#pragma unroll
  for (int kh = 0; kh < 7; ++kh) {
    short8 a0 = *(const short8*)(baseA[0] + kh * 928);
    short8 a1 = *(const short8*)(baseA[1] + kh * 928);
    const uint16_t* Bk = sB + kh * 2048;
#pragma unroll
    for (int j = 0; j < 4; ++j) {
      short8 bj = *(const short8*)(Bk + (16 * j + mrow) * 32 + ksw);
      acc[0][j] = mfma16(a0, bj, acc[0][j]);
      acc[1][j] = mfma16(a1, bj, acc[1][j]);
    }
  }

#pragma unroll
  for (int i = 0; i < 2; ++i) {
    int rbase = wm + 16 * i;
    int cellidx = blk * 2 + (rbase >> 6);
    if (cellidx >= cnt) continue;
    int cell = sc[rbase >> 6];
    int b = cell / 196, cc = cell - b * 196;
    int ci = cc / 14, cj = cc - ci * 14;
#pragma unroll
    for (int j = 0; j < 4; ++j) {
      int oc = 16 * j + mrow;
#pragma unroll
      for (int r = 0; r < 4; ++r) {
        int row = rbase + kg * 4 + r;
        int p = row & 63;
        int oh = ci * 8 + (p >> 3), ow = cj * 8 + (p & 7);
        float v = acc[i][j][r];
        v = v > 0.f ? v : 0.f;
        y1[(((size_t)(b * 112 + oh)) * 112 + ow) * 64 + oc] = f2bf(v);
      }
    }
  }
}

// ---------------- stage 4: MaxBlurPool1 (112 -> 56), mask-aware, writes padded p1 ----------------
__global__ __launch_bounds__(256) void k_pool1(const uint16_t* __restrict__ y1, const int* __restrict__ masks,
                                               uint16_t* __restrict__ p1) {
  __shared__ uint16_t sY[18 * 18 * 64];  // 41,472 B
  int b = blockIdx.y;
  int tile = blockIdx.x;
  int tr = tile >> 3, tc = tile & 7;
  int pr0 = tr * 8, pc0 = tc * 8;
  int R0 = 2 * pr0 - 7, C0 = 2 * pc0 - 7;
  int tid = threadIdx.x;
  const int* mb = masks + b * 196;

  for (int idx = tid; idx < 2592; idx += 256) {
    int pix = idx >> 3, ch = idx & 7;
    int pr = pix / 18, pc = pix - pr * 18;
    int r = R0 + pr, c = C0 + pc;
    short8 v = {0, 0, 0, 0, 0, 0, 0, 0};
    if ((unsigned)r < 112u && (unsigned)c < 112u && mb[(r >> 3) * 14 + (c >> 3)])
      v = *(const short8*)(y1 + (((size_t)(b * 112 + r)) * 112 + c) * 64 + ch * 8);
    *(short8*)(sY + ((size_t)(pr * 18 + pc)) * 64 + ch * 8) = v;
  }
  __syncthreads();

  for (int it = tid; it < 512; it += 256) {
    int opix = it >> 3, ch = it & 7;
    int lr = opix >> 3, lc = opix & 7;
    int pr = pr0 + lr, pc = pc0 + lc;
    if (pr >= 62 || pc >= 62) continue;
    int oh = pr - 3, ow = pc - 3;
    float acc[8] = {0.f, 0.f, 0.f, 0.f, 0.f, 0.f, 0.f, 0.f};
    if ((unsigned)oh < 56u && (unsigned)ow < 56u) {
      float hm_prev[3][8];
#pragma unroll
      for (int dd = 0; dd < 4; ++dd) {
        float yv[4][8];
        const uint16_t* src = sY + ((size_t)((2 * lr + dd) * 18 + 2 * lc)) * 64 + ch * 8;
#pragma unroll
        for (int e = 0; e < 4; ++e) {
          short8 t8 = *(const short8*)(src + e * 64);
#pragma unroll
          for (int k = 0; k < 8; ++k) yv[e][k] = bf2f((uint16_t)t8[k]);
        }
        float hm[3][8];
#pragma unroll
        for (int e = 0; e < 3; ++e) {
          int qc = 2 * ow - 1 + e;
          float cv = ((unsigned)qc <= 110u) ? 1.f : 0.f;
#pragma unroll
          for (int k = 0; k < 8; ++k) hm[e][k] = cv * fmaxf(yv[e][k], yv[e + 1][k]);
        }
        if (dd > 0) {
          int d = dd - 1;
          int qr = 2 * oh - 1 + d;
          if ((unsigned)qr <= 110u) {
            float wd = (d == 1) ? 2.f : 1.f;
#pragma unroll
            for (int e = 0; e < 3; ++e) {
              float w = wd * ((e == 1) ? 2.f : 1.f);
#pragma unroll
              for (int k = 0; k < 8; ++k) acc[k] += w * fmaxf(hm_prev[e][k], hm[e][k]);
            }
          }
        }
#pragma unroll
        for (int e = 0; e < 3; ++e)
#pragma unroll
          for (int k = 0; k < 8; ++k) hm_prev[e][k] = hm[e][k];
      }
#pragma unroll
      for (int k = 0; k < 8; ++k) acc[k] *= (1.f / 16.f);
    }
    short8 o;
#pragma unroll
    for (int k = 0; k < 8; ++k) o[k] = (short)f2bf(acc[k]);
    *(short8*)(p1 + (((size_t)(b * 62 + pr)) * 62 + pc) * 64 + ch * 8) = o;
  }
}

// ---------------- stage 5: conv2 (7x7 s2) — MFMA 128x128, 4 waves, 2-barrier, piped ks ----------
// = R6/R9 verbatim (measured best: 119.7-122.4us, MfmaUtil 47%, VGPR 80, no spill).
// Session-verified coupling: 128^2 tile (2352 blocks -> 9.2/CU packing) + ALL-16-ds_reads-up-front
// (ks1 burst overlaps ks0 MFMA; needs <=16 live frags -> N=64/wave) + (256,3) VGPR headroom.
// Alternatives all regressed on HW: M=256 serial-ks (R8 -26%), dbuf 64KB (R7 -13%), dbuf 96KB
// (R1 -8%), direct-reg A (R2 -2.6x), (256,5) spill (R4 -80%). DO NOT restructure without new data.
__global__ __launch_bounds__(256, 3) void k_conv2(const uint16_t* __restrict__ p1, const uint16_t* __restrict__ w2t,
                                                  const int* __restrict__ list, const int* __restrict__ count,
                                                  uint16_t* __restrict__ y2) {
  __shared__ uint16_t sA[128 * 64];   // 16 KB  A[row][ic]
  __shared__ uint16_t sBt[128 * 64];  // 16 KB  B^T[oc][ic]
  __shared__ int scs[32];

  int cnt = *count;
  int gx = blockIdx.x;
  int xcd = gx & 7, s = gx >> 3;
  int y = s % 6, mtl = s / 6;
  int mt = xcd + 8 * mtl;            // 0..391
  if (mt * 32 >= cnt) return;
  int ocb = y * 128;
  int tid = threadIdx.x, lane = tid & 63, wave = tid >> 6;   // 4 waves
  int csw = (lane & 7) ^ ((lane >> 3) & 7);

  if (tid < 32) scs[tid] = list[imin(mt * 32 + tid, cnt - 1)];
  __syncthreads();

  int qm = wave & 1, qn = wave >> 1;
  int mrow = lane & 15, kg = lane >> 4;

  // A staging: rows r = wave*32 + t*8 + (lane>>3), t=0..3 -> 128 rows; chunk csw pre-swizzled.
  const char* gA[4];
#pragma unroll
  for (int t = 0; t < 4; ++t) {
    int r = wave * 32 + t * 8 + (lane >> 3);
    int cell = scs[r >> 2];
    int b = cell / 196, cc = cell - b * 196;
    int ci = cc / 14, cj = cc - ci * 14;
    int p = r & 3;
    int oh = 2 * ci + (p >> 1), ow = 2 * cj + (p & 1);
    gA[t] = (const char*)p1 + (((size_t)(b * 62 + 2 * oh)) * 62 + 2 * ow) * 128 + csw * 16;
  }
  // B staging: oc rows wave*32 + t*8 + (lane>>3), t=0..3 -> 128 oc.
  const char* gB[4];
#pragma unroll
  for (int t = 0; t < 4; ++t) {
    int oc = ocb + wave * 32 + t * 8 + (lane >> 3);
    gB[t] = (const char*)w2t + (size_t)oc * 128 + csw * 16;
  }

  f32x4 acc[4][4];
#pragma unroll
  for (int i = 0; i < 4; ++i)
#pragma unroll
    for (int j = 0; j < 4; ++j) acc[i][j] = f32x4{0.f, 0.f, 0.f, 0.f};

  int sw8 = mrow & 7;
  int kh = 0, kw = 0;
  char* la = (char*)sA + wave * 4096;
  char* lb = (char*)sBt + wave * 4096;
  int k0 = (kg ^ sw8) * 8;          // ks=0 chunk offset (elems)
  int k1 = ((4 + kg) ^ sw8) * 8;    // ks=1 chunk offset

#pragma unroll 1
  for (int it = 0; it < 49; ++it) {
    size_t offA = (size_t)(kh * 62 + kw) * 128;
    size_t offB = (size_t)it * 98304;   // 768*64 elems * 2 B per tap
#pragma unroll
    for (int t = 0; t < 4; ++t) gl_lds16(gA[t] + offA, la + t * 1024);
#pragma unroll
    for (int t = 0; t < 4; ++t) gl_lds16(gB[t] + offB, lb + t * 1024);
    __syncthreads();
    // issue ALL 16 ds_reads (both k-slices) before any MFMA
    short8 a0[4], b0[4], a1[4], b1[4];
#pragma unroll
    for (int i = 0; i < 4; ++i)
      a0[i] = *(const short8*)(sA + (qm * 64 + 16 * i + mrow) * 64 + k0);
#pragma unroll
    for (int j = 0; j < 4; ++j)
      b0[j] = *(const short8*)(sBt + (qn * 64 + 16 * j + mrow) * 64 + k0);
#pragma unroll
    for (int i = 0; i < 4; ++i)
      a1[i] = *(const short8*)(sA + (qm * 64 + 16 * i + mrow) * 64 + k1);
#pragma unroll
    for (int j = 0; j < 4; ++j)
      b1[j] = *(const short8*)(sBt + (qn * 64 + 16 * j + mrow) * 64 + k1);
    __builtin_amdgcn_sched_barrier(0);   // all reads issued; nothing sinks below
    __builtin_amdgcn_s_setprio(1);
#pragma unroll
    for (int i = 0; i < 4; ++i)
#pragma unroll
      for (int j = 0; j < 4; ++j)
        acc[i][j] = mfma16(a0[i], b0[j], acc[i][j]);   // waits only ks0's 8 reads
    __builtin_amdgcn_s_setprio(0);
    __builtin_amdgcn_sched_barrier(0);
    __builtin_amdgcn_s_setprio(1);
#pragma unroll
    for (int i = 0; i < 4; ++i)
#pragma unroll
      for (int j = 0; j < 4; ++j)
        acc[i][j] = mfma16(a1[i], b1[j], acc[i][j]);
    __builtin_amdgcn_s_setprio(0);
    __syncthreads();
    if (++kw == 7) { kw = 0; ++kh; }
  }

  // epilogue: relu, write y2 NHWC bf16 (active rows only)
#pragma unroll
  for (int i = 0; i < 4; ++i) {
    int cellslot = qm * 16 + 4 * i + kg;
    int cellidx = mt * 32 + cellslot;
    if (cellidx >= cnt) continue;
    int cell = scs[cellslot];
    int b = cell / 196, cc = cell - b * 196;
    int ci = cc / 14, cj = cc - ci * 14;
#pragma unroll
    for (int j = 0; j < 4; ++j) {
      int oc = ocb + qn * 64 + 16 * j + mrow;
#pragma unroll
      for (int r = 0; r < 4; ++r) {
        int oh = 2 * ci + (r >> 1), ow = 2 * cj + (r & 1);
        float v = acc[i][j][r];
        v = v > 0.f ? v : 0.f;
        y2[(((size_t)(b * 784)) + oh * 28 + ow) * 768 + oc] = f2bf(v);
      }
    }
  }
}

// ---------------- stage 6: MaxBlurPool2 (28 -> 14) + transpose to [B,196,768] fp32 ----------------
// R11: compute phase vectorized 8-ch (short8 LDS reads). Old: 1792 items x 16 scalar ds_read_u16
// = 28672 scalar LDS reads/block (LDS-issue-bound). New: 224 items (pj x ch-group) x 16
// ds_read_b128. Same tap-guard semantics; fmax grouping preserved (vertical pairs then horiz max).
__global__ __launch_bounds__(256) void k_pool2(const uint16_t* __restrict__ y2, const int* __restrict__ masks,
                                               float* __restrict__ out) {
  __shared__ uint16_t sY[4 * 28 * 128];   // 28,672 B
  int chunk = blockIdx.x, pi = blockIdx.y, b = blockIdx.z;
  int ch0 = chunk * 128;
  int tid = threadIdx.x;
  const int* mb = masks + b * 196;

  for (int idx = tid; idx < 1792; idx += 256) {
    int rc = idx >> 4;
    int sub = idx & 15;
    int k = rc / 28, c = rc - k * 28;
    int r = 2 * pi - 1 + k;
    short8 v = {0, 0, 0, 0, 0, 0, 0, 0};
    if ((unsigned)r < 28u && mb[(r >> 1) * 14 + (c >> 1)])
      v = *(const short8*)(y2 + (((size_t)(b * 784)) + r * 28 + c) * 768 + ch0 + sub * 8);
    *(short8*)(sY + ((size_t)(k * 28 + c)) * 128 + sub * 8) = v;
  }
  __syncthreads();

  if (tid < 224) {
    int pj = tid >> 4, chg = tid & 15;
    float gd[3];
#pragma unroll
    for (int d = 0; d < 3; ++d) {
      int q = 2 * pi - 1 + d;
      gd[d] = ((unsigned)q <= 26u) ? ((d == 1) ? 2.f : 1.f) : 0.f;
    }
    float acc[8] = {0.f, 0.f, 0.f, 0.f, 0.f, 0.f, 0.f, 0.f};
    float pvp[3][8];
#pragma unroll
    for (int e = 0; e < 4; ++e) {
      int col = 2 * pj - 1 + e;
      float f[4][8];
      if ((unsigned)col < 28u) {
#pragma unroll
        for (int k = 0; k < 4; ++k) {
          short8 t8 = *(const short8*)(sY + ((size_t)(k * 28 + col)) * 128 + chg * 8);
#pragma unroll
          for (int j = 0; j < 8; ++j) f[k][j] = bf2f((uint16_t)t8[j]);
        }
      } else {
#pragma unroll
        for (int k = 0; k < 4; ++k)
#pragma unroll
          for (int j = 0; j < 8; ++j) f[k][j] = 0.f;
      }
      float pvc[3][8];
#pragma unroll
      for (int d = 0; d < 3; ++d)
#pragma unroll
        for (int j = 0; j < 8; ++j) pvc[d][j] = fmaxf(f[d][j], f[d + 1][j]);
      if (e > 0) {
        int tap = e - 1;
        int q2 = 2 * pj - 1 + tap;
        float ge = ((unsigned)q2 <= 26u) ? ((tap == 1) ? 2.f : 1.f) : 0.f;
#pragma unroll
        for (int d = 0; d < 3; ++d) {
          float w = gd[d] * ge;
#pragma unroll
          for (int j = 0; j < 8; ++j) acc[j] += w * fmaxf(pvp[d][j], pvc[d][j]);
        }
      }
#pragma unroll
      for (int d = 0; d < 3; ++d)
#pragma unroll
        for (int j = 0; j < 8; ++j) pvp[d][j] = pvc[d][j];
    }
    float* po = out + (((size_t)(b * 196)) + pi * 14 + pj) * 768 + ch0 + chg * 8;
#pragma unroll
    for (int j = 0; j < 8; ++j) po[j] = acc[j] * (1.f / 16.f);
  }
}

// ---------------- launcher ----------------
extern "C" void kernel_launch(void* const* d_in, const int* in_sizes, int n_in,
                              void* d_out, int out_size, void* d_ws, size_t ws_size,
                              hipStream_t stream) {
  const float* x     = (const float*)d_in[0];
  const int*   masks = (const int*)d_in[1];
  const float* w1    = (const float*)d_in[2];
  const float* w2    = (const float*)d_in[3];

  char* ws = (char*)d_ws;
  if (ws_size < WS_NEED) return;

  uint16_t* xp  = (uint16_t*)(ws + OFF_XP);
  uint16_t* w1t = (uint16_t*)(ws + OFF_W1T);
  uint16_t* w2t = (uint16_t*)(ws + OFF_W2T);
  uint16_t* y1  = (uint16_t*)(ws + OFF_Y1);
  uint16_t* p1  = (uint16_t*)(ws + OFF_P1);
  uint16_t* y2  = (uint16_t*)(ws + OFF_Y2);
  int* list     = (int*)(ws + OFF_LIST);
  int* cnts     = (int*)(ws + OFF_CNT);
  int* total    = cnts + 49;

  // fused front end: block 0 = count+emit (single-block prefix), 1..13456 = prep, rest = wt
  k_front<<<22921, 256, 0, stream>>>(masks, x, w1, w2, list, total, xp, w1t, w2t);
  k_conv1<<<6272, 256, 0, stream>>>(xp, w1t, list, total, y1);
  k_pool1<<<dim3(64, 64), 256, 0, stream>>>(y1, masks, p1);
  // 8 XCDs x 49 mt-slots x 6 oc-slices = 2352 blocks (M=128 tiles); 6 slices of an mt are
  // consecutive same-XCD ids (gx = xcd + 8*(mtl*6 + y)) for A-tile L2 reuse.
  k_conv2<<<2352, 256, 0, stream>>>(p1, w2t, list, total, y2);
  k_pool2<<<dim3(6, 14, 64), 256, 0, stream>>>(y2, masks, (float*)d_out);
}